// Round 11
// baseline (770.374 us; speedup 1.0000x reference)
//
#include <hip/hip_runtime.h>
#include <stdint.h>
#include <string.h>

// ---------------- problem constants ----------------
#define NV      4667
#define BB      4
#define TT      8
#define TPX     18
#define HID     16
#define NROOTS  500
#define NPATHS  7500
#define NEDGES  7000
#define NLEAF   4000
#define NP2     4864   // 19*256 row padding (M and N)
#define LDKQ    5120   // i8 K row bytes: 74 processed tiles*64 + prefetch pad (77*64=4928 <= 5120)
#define NSIGM   20
#define NSIGK   76

typedef __bf16 bf16;
typedef bf16  bf16x4 __attribute__((ext_vector_type(4)));
typedef int   i32x4v __attribute__((ext_vector_type(4)));
typedef const void __attribute__((address_space(1))) gvoid;
typedef void       __attribute__((address_space(3))) svoid;

// ============================================================
// Host-side exact replication of np.random.RandomState(42) tree
// ============================================================
struct MT19937 {
    uint32_t mt[624]; int pos;
    void seed(uint32_t s) {
        for (int i = 0; i < 624; ++i) { mt[i] = s; s = 1812433253u * (s ^ (s >> 30)) + (uint32_t)i + 1u; }
        pos = 624;
    }
    uint32_t next() {
        if (pos >= 624) {
            for (int i = 0; i < 624; ++i) {
                uint32_t y = (mt[i] & 0x80000000u) | (mt[(i + 1) % 624] & 0x7fffffffu);
                uint32_t v = mt[(i + 397) % 624] ^ (y >> 1);
                if (y & 1u) v ^= 0x9908b0dfu;
                mt[i] = v;
            }
            pos = 0;
        }
        uint32_t y = mt[pos++];
        y ^= y >> 11; y ^= (y << 7) & 0x9d2c5680u; y ^= (y << 15) & 0xefc60000u; y ^= y >> 18;
        return y;
    }
    uint32_t interval(uint32_t mx) {
        if (!mx) return 0;
        uint32_t mask = mx;
        mask |= mask >> 1; mask |= mask >> 2; mask |= mask >> 4; mask |= mask >> 8; mask |= mask >> 16;
        uint32_t v;
        do { v = next() & mask; } while (v > mx);
        return v;
    }
};

struct TreeBlob {
    int path_node[NPATHS];
    int leaf_start[NV + 1];
    int leaf_path[NLEAF];
};

static void build_tree_host(TreeBlob* tb) {
    MT19937 rng; rng.seed(42);
    static int perm[NV];
    auto choice_take = [&](int* out, int k) {
        for (int i = 0; i < NV; ++i) perm[i] = i;
        for (int i = NV - 1; i >= 1; --i) {
            int j = (int)rng.interval((uint32_t)i);
            int t = perm[i]; perm[i] = perm[j]; perm[j] = t;
        }
        for (int i = 0; i < k; ++i) out[i] = perm[i];
    };
    int np_ = 0;
    int roots[NROOTS];
    choice_take(roots, NROOTS);
    for (int i = 0; i < NROOTS; ++i) tb->path_node[np_++] = roots[i];
    int prev_cnt = NROOTS;
    for (int lvl = 0; lvl < 3; ++lvl) {
        int kids[2];
        for (int p = 0; p < prev_cnt; ++p) {
            choice_take(kids, 2);
            tb->path_node[np_++] = kids[0];
            tb->path_node[np_++] = kids[1];
        }
        prev_cnt *= 2;
    }
    static int cnt[NV], cur[NV];
    memset(cnt, 0, sizeof(cnt));
    for (int l = 0; l < NLEAF; ++l) cnt[tb->path_node[3500 + l]]++;
    tb->leaf_start[0] = 0;
    for (int n = 0; n < NV; ++n) tb->leaf_start[n + 1] = tb->leaf_start[n] + cnt[n];
    for (int n = 0; n < NV; ++n) cur[n] = tb->leaf_start[n];
    for (int l = 0; l < NLEAF; ++l) {
        int n = tb->path_node[3500 + l];
        tb->leaf_path[cur[n]++] = 3500 + l;
    }
}

static TreeBlob* get_pinned_tree() {
    static TreeBlob* p = [] {
        TreeBlob* q = nullptr;
        if (hipHostMalloc((void**)&q, sizeof(TreeBlob), 0) != hipSuccess || !q) {
            static TreeBlob fallback;
            q = &fallback;
        }
        build_tree_host(q);
        return q;
    }();
    return p;
}

// ============================================================
// Fused front: TimeBlock x3 + concat -> x, and lhs/rhs in one pass.
// One thread per (b,n); 16-float sliding window, no x re-read.
// ============================================================
__global__ __launch_bounds__(256)
void k_front(const float* __restrict__ X, const float* __restrict__ Xd,
             const float* __restrict__ Xw,
             const float* __restrict__ w1, const float* __restrict__ b1,
             const float* __restrict__ w2, const float* __restrict__ b2,
             const float* __restrict__ W1, const float* __restrict__ W2,
             const float* __restrict__ W3,
             float* __restrict__ x, float* __restrict__ lhs, float* __restrict__ rhs) {
    int idx = blockIdx.x * 256 + threadIdx.x;
    if (idx >= BB * NV) return;
    float l[16], r[16];
#pragma unroll
    for (int c = 0; c < 16; ++c) { l[c] = 0.f; r[c] = 0.f; }
    float* xo = x + (size_t)idx * TPX * HID;

    for (int g = 0; g < 3; ++g) {
        const float* Xg = (g == 0) ? X : (g == 1) ? Xd : Xw;
        const float* p = Xg + (size_t)idx * (TT * 2);
        float xr[16];
#pragma unroll
        for (int i = 0; i < 16; ++i) xr[i] = p[i];
#pragma unroll
        for (int t = 0; t < 6; ++t) {
            int tt = g * 6 + t;
            float w3 = W3[tt];
            float xt = 0.f;
            float outv[16];
#pragma unroll
            for (int o = 0; o < 16; ++o) {
                float c1 = b1[o], c2 = b2[o];
#pragma unroll
                for (int ci = 0; ci < 2; ++ci)
#pragma unroll
                    for (int kk = 0; kk < 3; ++kk) {
                        float xv = xr[(t + kk) * 2 + ci];
                        c1 += xv * w1[(o * 2 + ci) * 3 + kk];
                        c2 += xv * w2[(o * 2 + ci) * 3 + kk];
                    }
                float v = c1 * (1.0f / (1.0f + __expf(-c2)));
                outv[o] = v;
                xt += v * W1[o];
                r[o] += w3 * v;
            }
#pragma unroll
            for (int o = 0; o < 16; ++o) l[o] += xt * W2[tt * 16 + o];
            float4* op = (float4*)(xo + tt * 16);
#pragma unroll
            for (int q = 0; q < 4; ++q) {
                float4 f; f.x = outv[q * 4]; f.y = outv[q * 4 + 1];
                f.z = outv[q * 4 + 2]; f.w = outv[q * 4 + 3];
                op[q] = f;
            }
        }
    }
    float4* lo = (float4*)(lhs + (size_t)idx * 16);
    float4* ro = (float4*)(rhs + (size_t)idx * 16);
#pragma unroll
    for (int q = 0; q < 4; ++q) {
        float4 fl; fl.x = l[q * 4]; fl.y = l[q * 4 + 1]; fl.z = l[q * 4 + 2]; fl.w = l[q * 4 + 3];
        float4 fr; fr.x = r[q * 4]; fr.y = r[q * 4 + 1]; fr.z = r[q * 4 + 2]; fr.w = r[q * 4 + 3];
        lo[q] = fl; ro[q] = fr;
    }
}

// Fused prep: blocks [0, NP2) quantize Vs rows (+ first 19 zero colsum);
// blocks [NP2, NP2+NSIGM*NSIGK) compute Sq.
__global__ __launch_bounds__(256)
void k_prep(const float* __restrict__ Vs, int8_t* __restrict__ Vq,
            float* __restrict__ sA, float* __restrict__ c0,
            const float* __restrict__ lhs, const float* __restrict__ rhs,
            const float* __restrict__ bs, int8_t* __restrict__ Sq,
            float* __restrict__ colsum) {
    __shared__ float wred[4];
    __shared__ int ired[4];
    __shared__ bf16 bss[64 * 260];
    int blk = blockIdx.x;
    int t = threadIdx.x;

    if (blk < NP2) {
        if (blk < 19) {
#pragma unroll
            for (int u = 0; u < 4; ++u) {
                int ii = blk * 1024 + u * 256 + t;
                if (ii < BB * NV) colsum[ii] = 0.f;
            }
        }
        int n = blk;
        int8_t* row_out = Vq + (size_t)n * LDKQ;
        if (n >= NV) {
            for (int m = t * 4; m < LDKQ; m += 1024) *(int*)(row_out + m) = 0;
            if (t == 0) { sA[n] = 0.f; c0[n] = 0.f; }
            return;
        }
        const float* row = Vs + (size_t)n * NV;
        float v[20];
        float mx = 0.f;
#pragma unroll
        for (int i = 0; i < 20; ++i) {
            int m = t + i * 256;
            v[i] = (m < NV) ? row[m] : 0.f;
            mx = fmaxf(mx, fabsf(v[i]));
        }
#pragma unroll
        for (int o = 32; o; o >>= 1) mx = fmaxf(mx, __shfl_xor(mx, o));
        if ((t & 63) == 0) wred[t >> 6] = mx;
        __syncthreads();
        mx = fmaxf(fmaxf(wred[0], wred[1]), fmaxf(wred[2], wred[3]));
        mx = fmaxf(mx, 1e-30f);
        float inv = 127.f / mx;
        int qs = 0;
#pragma unroll
        for (int i = 0; i < 20; ++i) {
            int q = (int)rintf(v[i] * inv);
            qs += q;
            row_out[t + i * 256] = (int8_t)q;
        }
#pragma unroll
        for (int o = 32; o; o >>= 1) qs += __shfl_xor(qs, o);
        if ((t & 63) == 0) ired[t >> 6] = qs;
        __syncthreads();
        if (t == 0) {
            int tot = ired[0] + ired[1] + ired[2] + ired[3];
            sA[n] = mx / 32258.f;                 // mx/(127*254)
            c0[n] = mx * (float)tot / 254.f;      // 0.5 * sum(Vs_deq)
        }
        return;
    }

    int bid = blk - NP2;
    int m0 = (bid % NSIGM) * 256;
    int k0 = (bid / NSIGM) * 64;

    for (int i = t; i < 256 * 64; i += 256) {
        int row = i >> 6, col = i & 63;
        int mg = m0 + row, kg = k0 + col;
        float v = (mg < NV && kg < NV) ? bs[(size_t)mg * NV + kg] : 0.f;
        bss[col * 260 + row] = (bf16)v;
    }
    __syncthreads();

    int ml = t & 63, kc = t >> 6;
    int mbase = m0 + ml * 4;

    for (int b = 0; b < BB; ++b) {
        float lv[4][16];
#pragma unroll
        for (int r = 0; r < 4; ++r) {
            int mg = mbase + r;
            if (mg < NV) {
                const float4* lp = (const float4*)&lhs[((size_t)b * NV + mg) * 16];
#pragma unroll
                for (int q = 0; q < 4; ++q) {
                    float4 f = lp[q];
                    lv[r][q * 4 + 0] = f.x; lv[r][q * 4 + 1] = f.y;
                    lv[r][q * 4 + 2] = f.z; lv[r][q * 4 + 3] = f.w;
                }
            } else {
#pragma unroll
                for (int c = 0; c < 16; ++c) lv[r][c] = 0.f;
            }
        }
#pragma unroll
        for (int kk = 0; kk < 16; ++kk) {
            int kl = kc * 16 + kk;
            int kg = k0 + kl;
            bool kvalid = (kg < NV);
            float rsv[16];
            if (kvalid) {
                const float4* rp = (const float4*)&rhs[((size_t)b * NV + kg) * 16];
#pragma unroll
                for (int q = 0; q < 4; ++q) {
                    float4 f = rp[q];
                    rsv[q * 4 + 0] = f.x; rsv[q * 4 + 1] = f.y;
                    rsv[q * 4 + 2] = f.z; rsv[q * 4 + 3] = f.w;
                }
            } else {
#pragma unroll
                for (int c = 0; c < 16; ++c) rsv[c] = 0.f;
            }
            bf16x4 bv = *(const bf16x4*)&bss[kl * 260 + ml * 4];
            int pack = 0;
#pragma unroll
            for (int r = 0; r < 4; ++r) {
                float dot = 0.f;
#pragma unroll
                for (int c = 0; c < 16; ++c) dot += lv[r][c] * rsv[c];
                float pv = dot + (float)bv[r];
                float s = 1.0f / (1.0f + __expf(-pv));
                int q = 0;
                if (kvalid && (mbase + r) < NV) q = (int)rintf(254.f * (s - 0.5f));
                pack |= (q & 0xff) << (8 * r);
            }
            *(int*)&Sq[((size_t)b * NP2 + kg) * LDKQ + mbase] = pack;
        }
    }
}

// ============================================================
// 256x256 i8 GEMM, BK=64, 4-region rotation, counted vmcnt(8),
// conflict-free swizzle key ((row>>1)&3). 1 block/CU, 512 thr.
// (r10-verified best: 410us, MfmaUtil 50, conflicts 0)
// ============================================================
#define RB0 0
#define RB1 32768
#define RB2 65536
#define RB3 98304

#define STAGE4(BUF, kt) { \
    const int8_t* _ga = gA + (size_t)(kt) * 64; \
    const int8_t* _gb = gB + (size_t)(kt) * 64; \
    __builtin_amdgcn_global_load_lds((gvoid*)(_ga),                      (svoid*)(ldsb + (BUF) + dst0), 16, 0, 0); \
    __builtin_amdgcn_global_load_lds((gvoid*)(_ga + (size_t)128 * LDKQ), (svoid*)(ldsb + (BUF) + dst0 + 8192), 16, 0, 0); \
    __builtin_amdgcn_global_load_lds((gvoid*)(_gb),                      (svoid*)(ldsb + (BUF) + dst0 + 16384), 16, 0, 0); \
    __builtin_amdgcn_global_load_lds((gvoid*)(_gb + (size_t)128 * LDKQ), (svoid*)(ldsb + (BUF) + dst0 + 24576), 16, 0, 0); }

#define RD(BUF) { \
    _Pragma("unroll") for (int mf = 0; mf < 8; ++mf) \
        af[mf] = *(const i32x4v*)(ldsb + (BUF) + arow + mf * 1024); \
    _Pragma("unroll") for (int nj = 0; nj < 4; ++nj) \
        bf[nj] = *(const i32x4v*)(ldsb + (BUF) + brow + nj * 1024); }

#define MM() { \
    __builtin_amdgcn_s_setprio(1); \
    _Pragma("unroll") for (int mf = 0; mf < 8; ++mf) \
    _Pragma("unroll") for (int nj = 0; nj < 4; ++nj) \
        acc[mf][nj] = __builtin_amdgcn_mfma_i32_16x16x64_i8(af[mf], bf[nj], acc[mf][nj], 0, 0, 0); \
    __builtin_amdgcn_s_setprio(0); }

#define WIN(CUR, STG, kt) { \
    STAGE4(STG, kt); \
    RD(CUR); \
    MM(); \
    asm volatile("s_waitcnt vmcnt(8)" ::: "memory"); \
    __builtin_amdgcn_s_barrier(); }

__global__ __launch_bounds__(512, 2)
void k_gemm64(const int8_t* __restrict__ Vq, const int8_t* __restrict__ Sq,
              const float* __restrict__ sA, const float* __restrict__ c0,
              float* __restrict__ colsum) {
    extern __shared__ char ldsb[];

    // bijective XCD swizzle (nwg=1444, q=180, r=4)
    int orig = blockIdx.x;
    int xcd = orig & 7, lin = orig >> 3;
    int wg = (xcd < 4) ? xcd * 181 + lin : 724 + (xcd - 4) * 180 + lin;
    int bi = wg % 19;
    int bk = (wg / 19) % 19;
    int bb = wg / 361;

    int t = threadIdx.x;
    int lane = t & 63, wv = t >> 6;
    int wr = wv >> 2, wc = wv & 3;
    int lr = lane & 15, lg = lane >> 4;

    int ck = (lg * 16) ^ (((lr >> 1) & 3) << 4);
    int arow = wr * 8192 + lr * 64 + ck;
    int brow = 16384 + wc * 4096 + lr * 64 + ck;

    int rl0 = t >> 2;
    int csw = ((t & 3) << 4) ^ (((t >> 3) & 3) << 4);
    const int8_t* gA = Vq + ((size_t)(bi * 256) + rl0) * LDKQ + csw;
    const int8_t* gB = Sq + ((size_t)bb * NP2 + (size_t)bk * 256 + rl0) * LDKQ + csw;
    int dst0 = t * 16;

    i32x4v acc[8][4];
#pragma unroll
    for (int i = 0; i < 8; ++i)
#pragma unroll
        for (int j = 0; j < 4; ++j) acc[i][j] = i32x4v{0, 0, 0, 0};

    i32x4v af[8], bf[4];

    STAGE4(RB0, 0);
    STAGE4(RB1, 1);
    STAGE4(RB2, 2);
    asm volatile("s_waitcnt vmcnt(8)" ::: "memory");
    __builtin_amdgcn_s_barrier();

    for (int q = 0; q < 18; ++q) {
        WIN(RB0, RB3, 4 * q + 3);
        WIN(RB1, RB0, 4 * q + 4);
        WIN(RB2, RB1, 4 * q + 5);
        WIN(RB3, RB2, 4 * q + 6);
    }
    WIN(RB0, RB3, 75);
    WIN(RB1, RB0, 76);
    asm volatile("s_waitcnt vmcnt(0)" ::: "memory");

    // epilogue: S = sA[row]*I + c0[row]; masked exp -> per-column atomic colsum
#pragma unroll
    for (int nj = 0; nj < 4; ++nj) {
        int col = bk * 256 + wc * 64 + nj * 16 + lr;
        float csum = 0.f;
#pragma unroll
        for (int mf = 0; mf < 8; ++mf) {
            int rowb = bi * 256 + wr * 128 + mf * 16 + lg * 4;
            float4 sa4 = *(const float4*)&sA[rowb];
            float4 c04 = *(const float4*)&c0[rowb];
            float sar[4] = {sa4.x, sa4.y, sa4.z, sa4.w};
            float c0r[4] = {c04.x, c04.y, c04.z, c04.w};
#pragma unroll
            for (int r = 0; r < 4; ++r) {
                float S = sar[r] * (float)acc[mf][nj][r] + c0r[r];
                csum += ((rowb + r) < NV && col < NV) ? __expf(S) : 0.f;
            }
        }
        csum += __shfl_xor(csum, 16);
        csum += __shfl_xor(csum, 32);
        if (lane < 16 && col < NV) atomicAdd(&colsum[(size_t)bb * NV + col], csum);
    }
}

// per-edge numerator (same i8 arithmetic) + A value
__global__ void k_edge(const int8_t* __restrict__ Vq, const int8_t* __restrict__ Sq,
                       const float* __restrict__ sA, const float* __restrict__ c0,
                       const float* __restrict__ colsum, const int* __restrict__ path_node,
                       float* __restrict__ a_edge) {
    int g = blockIdx.x;
    int b = threadIdx.x >> 6;
    int lane = threadIdx.x & 63;
    int e, pbase, cbase;
    if (g < 1000)      { e = g;        pbase = 0;    cbase = 500;  }
    else if (g < 3000) { e = g - 1000; pbase = 500;  cbase = 1500; }
    else               { e = g - 3000; pbase = 1500; cbase = 3500; }
    int pn = path_node[pbase + (e >> 1)];
    int cn = path_node[cbase + e];
    const int8_t* va = Vq + (size_t)pn * LDKQ;
    const int8_t* vb = Sq + ((size_t)b * NP2 + cn) * LDKQ;
    int acc = 0;
    for (int i = lane * 16; i < LDKQ; i += 1024) {
        i32x4v a4 = *(const i32x4v*)(va + i);
        i32x4v b4 = *(const i32x4v*)(vb + i);
#pragma unroll
        for (int w = 0; w < 4; ++w) {
            int aw = a4[w], bw = b4[w];
#pragma unroll
            for (int q = 0; q < 4; ++q)
                acc += (int)(int8_t)(aw >> (8 * q)) * (int)(int8_t)(bw >> (8 * q));
        }
    }
#pragma unroll
    for (int o = 32; o; o >>= 1) acc += __shfl_xor(acc, o);
    if (lane == 0) {
        float S = sA[pn] * (float)acc + c0[pn];
        a_edge[(size_t)g * BB + b] = __expf(S) / colsum[(size_t)b * NV + cn];
    }
}

// one tree level, 1 thread per (e,b,t), 16 outputs/thread.
__global__ __launch_bounds__(256)
void k_level(const float* __restrict__ x, const int* __restrict__ path_node,
             const float* __restrict__ fcw, const float* __restrict__ fcb,
             const float* __restrict__ a_edge, float* __restrict__ H,
             int E, int pbase, int cbase, int gbase, int lvl1) {
    int idx = blockIdx.x * 256 + threadIdx.x;
    if (idx >= E * BB * TPX) return;
    int t = idx % TPX;
    int b = (idx / TPX) & 3;
    int e = idx / (TPX * BB);
    int pp = pbase + (e >> 1);
    const float* hp;
    if (lvl1) {
        int pn = path_node[pp];
        hp = &x[(((size_t)b * NV + pn) * TPX + t) * HID];
    } else {
        hp = &H[(((size_t)pp * BB + b) * TPX + t) * HID];
    }
    float h[16];
    const float4* hp4 = (const float4*)hp;
#pragma unroll
    for (int q = 0; q < 4; ++q) {
        float4 f = hp4[q];
        h[q * 4 + 0] = f.x; h[q * 4 + 1] = f.y; h[q * 4 + 2] = f.z; h[q * 4 + 3] = f.w;
    }
    float a = a_edge[(size_t)(gbase + e) * BB + b];
    int cp = cbase + e;
    int cn = path_node[cp];
    const float4* xv4 = (const float4*)&x[(((size_t)b * NV + cn) * TPX + t) * HID];
    float4* outp = (float4*)&H[(((size_t)cp * BB + b) * TPX + t) * HID];
#pragma unroll
    for (int q = 0; q < 4; ++q) {
        float4 xv = xv4[q];
        float o[4];
#pragma unroll
        for (int j = 0; j < 4; ++j) {
            int d = q * 4 + j;
            float acc = fcb[d];
#pragma unroll
            for (int c = 0; c < 16; ++c) acc += h[c] * fcw[d * 16 + c];
            o[j] = acc * a;
        }
        float4 ov; ov.x = o[0] + xv.x; ov.y = o[1] + xv.y; ov.z = o[2] + xv.z; ov.w = o[3] + xv.w;
        outp[q] = ov;
    }
}

__global__ void k_pool(const float* __restrict__ x, const float* __restrict__ H,
                       const int* __restrict__ leaf_start, const int* __restrict__ leaf_path,
                       float* __restrict__ out) {
    int n = blockIdx.x;
    int s = leaf_start[n], epos = leaf_start[n + 1];
    int cnt = epos - s;
    for (int idx = threadIdx.x; idx < BB * 288; idx += 256) {
        int b = idx / 288, d = idx % 288;
        float v;
        if (cnt == 0) {
            v = x[((size_t)b * NV + n) * 288 + d];
        } else {
            float sum = 0.f;
            for (int l = s; l < epos; ++l) {
                int p = leaf_path[l];
                sum += H[((size_t)p * BB + b) * 288 + d];
            }
            v = sum / (float)cnt;
        }
        out[((size_t)b * NV + n) * 288 + d] = v;
    }
}

// ============================================================
// Launch
// ============================================================
extern "C" void kernel_launch(void* const* d_in, const int* in_sizes, int n_in,
                              void* d_out, int out_size, void* d_ws, size_t ws_size,
                              hipStream_t stream) {
    const float* X   = (const float*)d_in[0];
    const float* Xd  = (const float*)d_in[1];
    const float* Xw  = (const float*)d_in[2];
    const float* c1w = (const float*)d_in[4];
    const float* c1b = (const float*)d_in[5];
    const float* c2w = (const float*)d_in[6];
    const float* c2b = (const float*)d_in[7];
    const float* W1  = (const float*)d_in[8];
    const float* W2  = (const float*)d_in[9];
    const float* W3  = (const float*)d_in[10];
    const float* bs  = (const float*)d_in[11];
    const float* Vs  = (const float*)d_in[12];
    const float* fcw = (const float*)d_in[13];
    const float* fcb = (const float*)d_in[14];
    float* out = (float*)d_out;

    TreeBlob* pinned = get_pinned_tree();

    char* w = (char*)d_ws;
    auto alloc = [&](size_t bytes) { char* p = w; w += (bytes + 255) & ~(size_t)255; return p; };
    float*  x      = (float*)alloc((size_t)BB * NV * 288 * 4);
    float*  lhs    = (float*)alloc((size_t)BB * NV * 16 * 4);
    float*  rhs    = (float*)alloc((size_t)BB * NV * 16 * 4);
    float*  colsum = (float*)alloc((size_t)BB * NV * 4);
    float*  aedge  = (float*)alloc((size_t)NEDGES * BB * 4);
    float*  H      = (float*)alloc((size_t)NPATHS * BB * 288 * 4);
    float*  sAr    = (float*)alloc((size_t)NP2 * 4);
    float*  c0r    = (float*)alloc((size_t)NP2 * 4);
    int*    dtree  = (int*)alloc(sizeof(TreeBlob));
    int8_t* Vq     = (int8_t*)alloc((size_t)NP2 * LDKQ);
    int8_t* Sq     = (int8_t*)alloc((size_t)BB * NP2 * LDKQ);

    int* d_path   = dtree;
    int* d_lstart = dtree + NPATHS;
    int* d_lpath  = d_lstart + (NV + 1);

    hipFuncSetAttribute((const void*)k_gemm64, hipFuncAttributeMaxDynamicSharedMemorySize, 131072);

    hipMemcpyAsync(dtree, pinned, sizeof(TreeBlob), hipMemcpyHostToDevice, stream);

    k_front<<<(BB * NV + 255) / 256, 256, 0, stream>>>(X, Xd, Xw, c1w, c1b, c2w, c2b,
                                                       W1, W2, W3, x, lhs, rhs);
    k_prep<<<NP2 + NSIGM * NSIGK, 256, 0, stream>>>(Vs, Vq, sAr, c0r, lhs, rhs, bs, Sq, colsum);
    k_gemm64<<<19 * 19 * BB, 512, 131072, stream>>>(Vq, Sq, sAr, c0r, colsum);
    k_edge<<<NEDGES, 256, 0, stream>>>(Vq, Sq, sAr, c0r, colsum, d_path, aedge);
    k_level<<<(1000 * BB * TPX + 255) / 256, 256, 0, stream>>>(x, d_path, fcw, fcb, aedge, H, 1000, 0, 500, 0, 1);
    k_level<<<(2000 * BB * TPX + 255) / 256, 256, 0, stream>>>(x, d_path, fcw, fcb, aedge, H, 2000, 500, 1500, 1000, 0);
    k_level<<<(4000 * BB * TPX + 255) / 256, 256, 0, stream>>>(x, d_path, fcw, fcb, aedge, H, 4000, 1500, 3500, 3000, 0);
    k_pool<<<NV, 256, 0, stream>>>(x, H, d_lstart, d_lpath, out);
}

// Round 12
// 712.098 us; speedup vs baseline: 1.0818x; 1.0818x over previous
//
#include <hip/hip_runtime.h>
#include <stdint.h>
#include <string.h>

// ---------------- problem constants ----------------
#define NV      4667
#define BB      4
#define TT      8
#define TPX     18
#define HID     16
#define NROOTS  500
#define NPATHS  7500
#define NEDGES  7000
#define NLEAF   4000
#define NP2     4864   // 19*256 row padding (M and N)
#define LDKQ    5120   // i8 K row bytes: 74 processed tiles*64 + prefetch pad (77*64=4928 <= 5120)
#define NSIGM   20
#define NSIGK   76

typedef __bf16 bf16;
typedef bf16  bf16x4 __attribute__((ext_vector_type(4)));
typedef int   i32x4v __attribute__((ext_vector_type(4)));
typedef const void __attribute__((address_space(1))) gvoid;
typedef void       __attribute__((address_space(3))) svoid;

// ============================================================
// Host-side exact replication of np.random.RandomState(42) tree
// ============================================================
struct MT19937 {
    uint32_t mt[624]; int pos;
    void seed(uint32_t s) {
        for (int i = 0; i < 624; ++i) { mt[i] = s; s = 1812433253u * (s ^ (s >> 30)) + (uint32_t)i + 1u; }
        pos = 624;
    }
    uint32_t next() {
        if (pos >= 624) {
            for (int i = 0; i < 624; ++i) {
                uint32_t y = (mt[i] & 0x80000000u) | (mt[(i + 1) % 624] & 0x7fffffffu);
                uint32_t v = mt[(i + 397) % 624] ^ (y >> 1);
                if (y & 1u) v ^= 0x9908b0dfu;
                mt[i] = v;
            }
            pos = 0;
        }
        uint32_t y = mt[pos++];
        y ^= y >> 11; y ^= (y << 7) & 0x9d2c5680u; y ^= (y << 15) & 0xefc60000u; y ^= y >> 18;
        return y;
    }
    uint32_t interval(uint32_t mx) {
        if (!mx) return 0;
        uint32_t mask = mx;
        mask |= mask >> 1; mask |= mask >> 2; mask |= mask >> 4; mask |= mask >> 8; mask |= mask >> 16;
        uint32_t v;
        do { v = next() & mask; } while (v > mx);
        return v;
    }
};

struct TreeBlob {
    int path_node[NPATHS];
    int leaf_start[NV + 1];
    int leaf_path[NLEAF];
};

static void build_tree_host(TreeBlob* tb) {
    MT19937 rng; rng.seed(42);
    static int perm[NV];
    auto choice_take = [&](int* out, int k) {
        for (int i = 0; i < NV; ++i) perm[i] = i;
        for (int i = NV - 1; i >= 1; --i) {
            int j = (int)rng.interval((uint32_t)i);
            int t = perm[i]; perm[i] = perm[j]; perm[j] = t;
        }
        for (int i = 0; i < k; ++i) out[i] = perm[i];
    };
    int np_ = 0;
    int roots[NROOTS];
    choice_take(roots, NROOTS);
    for (int i = 0; i < NROOTS; ++i) tb->path_node[np_++] = roots[i];
    int prev_cnt = NROOTS;
    for (int lvl = 0; lvl < 3; ++lvl) {
        int kids[2];
        for (int p = 0; p < prev_cnt; ++p) {
            choice_take(kids, 2);
            tb->path_node[np_++] = kids[0];
            tb->path_node[np_++] = kids[1];
        }
        prev_cnt *= 2;
    }
    static int cnt[NV], cur[NV];
    memset(cnt, 0, sizeof(cnt));
    for (int l = 0; l < NLEAF; ++l) cnt[tb->path_node[3500 + l]]++;
    tb->leaf_start[0] = 0;
    for (int n = 0; n < NV; ++n) tb->leaf_start[n + 1] = tb->leaf_start[n] + cnt[n];
    for (int n = 0; n < NV; ++n) cur[n] = tb->leaf_start[n];
    for (int l = 0; l < NLEAF; ++l) {
        int n = tb->path_node[3500 + l];
        tb->leaf_path[cur[n]++] = 3500 + l;
    }
}

static TreeBlob* get_pinned_tree() {
    static TreeBlob* p = [] {
        TreeBlob* q = nullptr;
        if (hipHostMalloc((void**)&q, sizeof(TreeBlob), 0) != hipSuccess || !q) {
            static TreeBlob fallback;
            q = &fallback;
        }
        build_tree_host(q);
        return q;
    }();
    return p;
}

// ============================================================
// Front kernels (r10-verified split versions)
// ============================================================
__global__ void k_timeblock(const float* __restrict__ X, const float* __restrict__ Xd,
                            const float* __restrict__ Xw,
                            const float* __restrict__ w1, const float* __restrict__ b1,
                            const float* __restrict__ w2, const float* __restrict__ b2,
                            float* __restrict__ x) {
    int idx = blockIdx.x * 256 + threadIdx.x;
    if (idx >= BB * NV * 18) return;
    int t = idx % 6;
    int g = (idx / 6) % 3;
    int n = (idx / 18) % NV;
    int b = idx / (18 * NV);
    const float* Xg = (g == 0) ? X : (g == 1) ? Xd : Xw;
    const float* p = Xg + (((size_t)b * NV + n) * TT + t) * 2;
    float v[6];
#pragma unroll
    for (int kk = 0; kk < 3; ++kk) { v[kk * 2 + 0] = p[kk * 2 + 0]; v[kk * 2 + 1] = p[kk * 2 + 1]; }
    float* xo = x + (((size_t)b * NV + n) * TPX + (g * 6 + t)) * HID;
#pragma unroll
    for (int o = 0; o < 16; ++o) {
        float c1 = b1[o], c2 = b2[o];
#pragma unroll
        for (int ci = 0; ci < 2; ++ci)
#pragma unroll
            for (int kk = 0; kk < 3; ++kk) {
                float xv = v[kk * 2 + ci];
                c1 += xv * w1[(o * 2 + ci) * 3 + kk];
                c2 += xv * w2[(o * 2 + ci) * 3 + kk];
            }
        xo[o] = c1 * (1.0f / (1.0f + __expf(-c2)));
    }
}

__global__ void k_lhsrhs(const float* __restrict__ x, const float* __restrict__ W1,
                         const float* __restrict__ W2, const float* __restrict__ W3,
                         float* __restrict__ lhs, float* __restrict__ rhs) {
    int idx = blockIdx.x * 256 + threadIdx.x;
    if (idx >= BB * NV) return;
    const float* xp = x + (size_t)idx * TPX * HID;
    float l[16], r[16];
#pragma unroll
    for (int c = 0; c < 16; ++c) { l[c] = 0.f; r[c] = 0.f; }
    for (int t = 0; t < TPX; ++t) {
        float xt = 0.f, w3 = W3[t];
#pragma unroll
        for (int c = 0; c < 16; ++c) { float xv = xp[t * 16 + c]; xt += xv * W1[c]; r[c] += w3 * xv; }
#pragma unroll
        for (int c = 0; c < 16; ++c) l[c] += xt * W2[t * 16 + c];
    }
    float* lo = lhs + (size_t)idx * 16;
    float* ro = rhs + (size_t)idx * 16;
#pragma unroll
    for (int c = 0; c < 16; ++c) { lo[c] = l[c]; ro[c] = r[c]; }
}

// Fused prep: blocks [0, NP2) quantize Vs rows (+ first 19 zero colsum);
// blocks [NP2, NP2+NSIGM*NSIGK) compute Sq.
__global__ __launch_bounds__(256)
void k_prep(const float* __restrict__ Vs, int8_t* __restrict__ Vq,
            float* __restrict__ sA, float* __restrict__ c0,
            const float* __restrict__ lhs, const float* __restrict__ rhs,
            const float* __restrict__ bs, int8_t* __restrict__ Sq,
            float* __restrict__ colsum) {
    __shared__ float wred[4];
    __shared__ int ired[4];
    __shared__ bf16 bss[64 * 260];
    int blk = blockIdx.x;
    int t = threadIdx.x;

    if (blk < NP2) {
        if (blk < 19) {
#pragma unroll
            for (int u = 0; u < 4; ++u) {
                int ii = blk * 1024 + u * 256 + t;
                if (ii < BB * NV) colsum[ii] = 0.f;
            }
        }
        int n = blk;
        int8_t* row_out = Vq + (size_t)n * LDKQ;
        if (n >= NV) {
            for (int m = t * 4; m < LDKQ; m += 1024) *(int*)(row_out + m) = 0;
            if (t == 0) { sA[n] = 0.f; c0[n] = 0.f; }
            return;
        }
        const float* row = Vs + (size_t)n * NV;
        float v[20];
        float mx = 0.f;
#pragma unroll
        for (int i = 0; i < 20; ++i) {
            int m = t + i * 256;
            v[i] = (m < NV) ? row[m] : 0.f;
            mx = fmaxf(mx, fabsf(v[i]));
        }
#pragma unroll
        for (int o = 32; o; o >>= 1) mx = fmaxf(mx, __shfl_xor(mx, o));
        if ((t & 63) == 0) wred[t >> 6] = mx;
        __syncthreads();
        mx = fmaxf(fmaxf(wred[0], wred[1]), fmaxf(wred[2], wred[3]));
        mx = fmaxf(mx, 1e-30f);
        float inv = 127.f / mx;
        int qs = 0;
#pragma unroll
        for (int i = 0; i < 20; ++i) {
            int q = (int)rintf(v[i] * inv);
            qs += q;
            row_out[t + i * 256] = (int8_t)q;
        }
#pragma unroll
        for (int o = 32; o; o >>= 1) qs += __shfl_xor(qs, o);
        if ((t & 63) == 0) ired[t >> 6] = qs;
        __syncthreads();
        if (t == 0) {
            int tot = ired[0] + ired[1] + ired[2] + ired[3];
            sA[n] = mx / 32258.f;                 // mx/(127*254)
            c0[n] = mx * (float)tot / 254.f;      // 0.5 * sum(Vs_deq)
        }
        return;
    }

    int bid = blk - NP2;
    int m0 = (bid % NSIGM) * 256;
    int k0 = (bid / NSIGM) * 64;

    for (int i = t; i < 256 * 64; i += 256) {
        int row = i >> 6, col = i & 63;
        int mg = m0 + row, kg = k0 + col;
        float v = (mg < NV && kg < NV) ? bs[(size_t)mg * NV + kg] : 0.f;
        bss[col * 260 + row] = (bf16)v;
    }
    __syncthreads();

    int ml = t & 63, kc = t >> 6;
    int mbase = m0 + ml * 4;

    for (int b = 0; b < BB; ++b) {
        float lv[4][16];
#pragma unroll
        for (int r = 0; r < 4; ++r) {
            int mg = mbase + r;
            if (mg < NV) {
                const float4* lp = (const float4*)&lhs[((size_t)b * NV + mg) * 16];
#pragma unroll
                for (int q = 0; q < 4; ++q) {
                    float4 f = lp[q];
                    lv[r][q * 4 + 0] = f.x; lv[r][q * 4 + 1] = f.y;
                    lv[r][q * 4 + 2] = f.z; lv[r][q * 4 + 3] = f.w;
                }
            } else {
#pragma unroll
                for (int c = 0; c < 16; ++c) lv[r][c] = 0.f;
            }
        }
#pragma unroll
        for (int kk = 0; kk < 16; ++kk) {
            int kl = kc * 16 + kk;
            int kg = k0 + kl;
            bool kvalid = (kg < NV);
            float rsv[16];
            if (kvalid) {
                const float4* rp = (const float4*)&rhs[((size_t)b * NV + kg) * 16];
#pragma unroll
                for (int q = 0; q < 4; ++q) {
                    float4 f = rp[q];
                    rsv[q * 4 + 0] = f.x; rsv[q * 4 + 1] = f.y;
                    rsv[q * 4 + 2] = f.z; rsv[q * 4 + 3] = f.w;
                }
            } else {
#pragma unroll
                for (int c = 0; c < 16; ++c) rsv[c] = 0.f;
            }
            bf16x4 bv = *(const bf16x4*)&bss[kl * 260 + ml * 4];
            int pack = 0;
#pragma unroll
            for (int r = 0; r < 4; ++r) {
                float dot = 0.f;
#pragma unroll
                for (int c = 0; c < 16; ++c) dot += lv[r][c] * rsv[c];
                float pv = dot + (float)bv[r];
                float s = 1.0f / (1.0f + __expf(-pv));
                int q = 0;
                if (kvalid && (mbase + r) < NV) q = (int)rintf(254.f * (s - 0.5f));
                pack |= (q & 0xff) << (8 * r);
            }
            *(int*)&Sq[((size_t)b * NP2 + kg) * LDKQ + mbase] = pack;
        }
    }
}

// ============================================================
// 256x256 i8 GEMM, BK=64, 4-region rotation, counted vmcnt(8),
// conflict-free swizzle key ((row>>1)&3). 1 block/CU, 512 thr.
// (r10-verified best: 410us, MfmaUtil 50, conflicts 0)
// ============================================================
#define RB0 0
#define RB1 32768
#define RB2 65536
#define RB3 98304

#define STAGE4(BUF, kt) { \
    const int8_t* _ga = gA + (size_t)(kt) * 64; \
    const int8_t* _gb = gB + (size_t)(kt) * 64; \
    __builtin_amdgcn_global_load_lds((gvoid*)(_ga),                      (svoid*)(ldsb + (BUF) + dst0), 16, 0, 0); \
    __builtin_amdgcn_global_load_lds((gvoid*)(_ga + (size_t)128 * LDKQ), (svoid*)(ldsb + (BUF) + dst0 + 8192), 16, 0, 0); \
    __builtin_amdgcn_global_load_lds((gvoid*)(_gb),                      (svoid*)(ldsb + (BUF) + dst0 + 16384), 16, 0, 0); \
    __builtin_amdgcn_global_load_lds((gvoid*)(_gb + (size_t)128 * LDKQ), (svoid*)(ldsb + (BUF) + dst0 + 24576), 16, 0, 0); }

#define RD(BUF) { \
    _Pragma("unroll") for (int mf = 0; mf < 8; ++mf) \
        af[mf] = *(const i32x4v*)(ldsb + (BUF) + arow + mf * 1024); \
    _Pragma("unroll") for (int nj = 0; nj < 4; ++nj) \
        bf[nj] = *(const i32x4v*)(ldsb + (BUF) + brow + nj * 1024); }

#define MM() { \
    __builtin_amdgcn_s_setprio(1); \
    _Pragma("unroll") for (int mf = 0; mf < 8; ++mf) \
    _Pragma("unroll") for (int nj = 0; nj < 4; ++nj) \
        acc[mf][nj] = __builtin_amdgcn_mfma_i32_16x16x64_i8(af[mf], bf[nj], acc[mf][nj], 0, 0, 0); \
    __builtin_amdgcn_s_setprio(0); }

#define WIN(CUR, STG, kt) { \
    STAGE4(STG, kt); \
    RD(CUR); \
    MM(); \
    asm volatile("s_waitcnt vmcnt(8)" ::: "memory"); \
    __builtin_amdgcn_s_barrier(); }

__global__ __launch_bounds__(512, 2)
void k_gemm64(const int8_t* __restrict__ Vq, const int8_t* __restrict__ Sq,
              const float* __restrict__ sA, const float* __restrict__ c0,
              float* __restrict__ colsum) {
    extern __shared__ char ldsb[];

    // bijective XCD swizzle (nwg=1444, q=180, r=4)
    int orig = blockIdx.x;
    int xcd = orig & 7, lin = orig >> 3;
    int wg = (xcd < 4) ? xcd * 181 + lin : 724 + (xcd - 4) * 180 + lin;
    int bi = wg % 19;
    int bk = (wg / 19) % 19;
    int bb = wg / 361;

    int t = threadIdx.x;
    int lane = t & 63, wv = t >> 6;
    int wr = wv >> 2, wc = wv & 3;
    int lr = lane & 15, lg = lane >> 4;

    int ck = (lg * 16) ^ (((lr >> 1) & 3) << 4);
    int arow = wr * 8192 + lr * 64 + ck;
    int brow = 16384 + wc * 4096 + lr * 64 + ck;

    int rl0 = t >> 2;
    int csw = ((t & 3) << 4) ^ (((t >> 3) & 3) << 4);
    const int8_t* gA = Vq + ((size_t)(bi * 256) + rl0) * LDKQ + csw;
    const int8_t* gB = Sq + ((size_t)bb * NP2 + (size_t)bk * 256 + rl0) * LDKQ + csw;
    int dst0 = t * 16;

    i32x4v acc[8][4];
#pragma unroll
    for (int i = 0; i < 8; ++i)
#pragma unroll
        for (int j = 0; j < 4; ++j) acc[i][j] = i32x4v{0, 0, 0, 0};

    i32x4v af[8], bf[4];

    STAGE4(RB0, 0);
    STAGE4(RB1, 1);
    STAGE4(RB2, 2);
    asm volatile("s_waitcnt vmcnt(8)" ::: "memory");
    __builtin_amdgcn_s_barrier();

    for (int q = 0; q < 18; ++q) {
        WIN(RB0, RB3, 4 * q + 3);
        WIN(RB1, RB0, 4 * q + 4);
        WIN(RB2, RB1, 4 * q + 5);
        WIN(RB3, RB2, 4 * q + 6);
    }
    WIN(RB0, RB3, 75);
    WIN(RB1, RB0, 76);
    asm volatile("s_waitcnt vmcnt(0)" ::: "memory");

    // epilogue: S = sA[row]*I + c0[row]; masked exp -> per-column atomic colsum
#pragma unroll
    for (int nj = 0; nj < 4; ++nj) {
        int col = bk * 256 + wc * 64 + nj * 16 + lr;
        float csum = 0.f;
#pragma unroll
        for (int mf = 0; mf < 8; ++mf) {
            int rowb = bi * 256 + wr * 128 + mf * 16 + lg * 4;
            float4 sa4 = *(const float4*)&sA[rowb];
            float4 c04 = *(const float4*)&c0[rowb];
            float sar[4] = {sa4.x, sa4.y, sa4.z, sa4.w};
            float c0r[4] = {c04.x, c04.y, c04.z, c04.w};
#pragma unroll
            for (int r = 0; r < 4; ++r) {
                float S = sar[r] * (float)acc[mf][nj][r] + c0r[r];
                csum += ((rowb + r) < NV && col < NV) ? __expf(S) : 0.f;
            }
        }
        csum += __shfl_xor(csum, 16);
        csum += __shfl_xor(csum, 32);
        if (lane < 16 && col < NV) atomicAdd(&colsum[(size_t)bb * NV + col], csum);
    }
}

// per-edge numerator (same i8 arithmetic) + A value
__global__ void k_edge(const int8_t* __restrict__ Vq, const int8_t* __restrict__ Sq,
                       const float* __restrict__ sA, const float* __restrict__ c0,
                       const float* __restrict__ colsum, const int* __restrict__ path_node,
                       float* __restrict__ a_edge) {
    int g = blockIdx.x;
    int b = threadIdx.x >> 6;
    int lane = threadIdx.x & 63;
    int e, pbase, cbase;
    if (g < 1000)      { e = g;        pbase = 0;    cbase = 500;  }
    else if (g < 3000) { e = g - 1000; pbase = 500;  cbase = 1500; }
    else               { e = g - 3000; pbase = 1500; cbase = 3500; }
    int pn = path_node[pbase + (e >> 1)];
    int cn = path_node[cbase + e];
    const int8_t* va = Vq + (size_t)pn * LDKQ;
    const int8_t* vb = Sq + ((size_t)b * NP2 + cn) * LDKQ;
    int acc = 0;
    for (int i = lane * 16; i < LDKQ; i += 1024) {
        i32x4v a4 = *(const i32x4v*)(va + i);
        i32x4v b4 = *(const i32x4v*)(vb + i);
#pragma unroll
        for (int w = 0; w < 4; ++w) {
            int aw = a4[w], bw = b4[w];
#pragma unroll
            for (int q = 0; q < 4; ++q)
                acc += (int)(int8_t)(aw >> (8 * q)) * (int)(int8_t)(bw >> (8 * q));
        }
    }
#pragma unroll
    for (int o = 32; o; o >>= 1) acc += __shfl_xor(acc, o);
    if (lane == 0) {
        float S = sA[pn] * (float)acc + c0[pn];
        a_edge[(size_t)g * BB + b] = __expf(S) / colsum[(size_t)b * NV + cn];
    }
}

// one tree level, 1 thread per (e,b,t), 16 outputs/thread.
__global__ __launch_bounds__(256)
void k_level(const float* __restrict__ x, const int* __restrict__ path_node,
             const float* __restrict__ fcw, const float* __restrict__ fcb,
             const float* __restrict__ a_edge, float* __restrict__ H,
             int E, int pbase, int cbase, int gbase, int lvl1) {
    int idx = blockIdx.x * 256 + threadIdx.x;
    if (idx >= E * BB * TPX) return;
    int t = idx % TPX;
    int b = (idx / TPX) & 3;
    int e = idx / (TPX * BB);
    int pp = pbase + (e >> 1);
    const float* hp;
    if (lvl1) {
        int pn = path_node[pp];
        hp = &x[(((size_t)b * NV + pn) * TPX + t) * HID];
    } else {
        hp = &H[(((size_t)pp * BB + b) * TPX + t) * HID];
    }
    float h[16];
    const float4* hp4 = (const float4*)hp;
#pragma unroll
    for (int q = 0; q < 4; ++q) {
        float4 f = hp4[q];
        h[q * 4 + 0] = f.x; h[q * 4 + 1] = f.y; h[q * 4 + 2] = f.z; h[q * 4 + 3] = f.w;
    }
    float a = a_edge[(size_t)(gbase + e) * BB + b];
    int cp = cbase + e;
    int cn = path_node[cp];
    const float4* xv4 = (const float4*)&x[(((size_t)b * NV + cn) * TPX + t) * HID];
    float4* outp = (float4*)&H[(((size_t)cp * BB + b) * TPX + t) * HID];
#pragma unroll
    for (int q = 0; q < 4; ++q) {
        float4 xv = xv4[q];
        float o[4];
#pragma unroll
        for (int j = 0; j < 4; ++j) {
            int d = q * 4 + j;
            float acc = fcb[d];
#pragma unroll
            for (int c = 0; c < 16; ++c) acc += h[c] * fcw[d * 16 + c];
            o[j] = acc * a;
        }
        float4 ov; ov.x = o[0] + xv.x; ov.y = o[1] + xv.y; ov.z = o[2] + xv.z; ov.w = o[3] + xv.w;
        outp[q] = ov;
    }
}

__global__ void k_pool(const float* __restrict__ x, const float* __restrict__ H,
                       const int* __restrict__ leaf_start, const int* __restrict__ leaf_path,
                       float* __restrict__ out) {
    int n = blockIdx.x;
    int s = leaf_start[n], epos = leaf_start[n + 1];
    int cnt = epos - s;
    for (int idx = threadIdx.x; idx < BB * 288; idx += 256) {
        int b = idx / 288, d = idx % 288;
        float v;
        if (cnt == 0) {
            v = x[((size_t)b * NV + n) * 288 + d];
        } else {
            float sum = 0.f;
            for (int l = s; l < epos; ++l) {
                int p = leaf_path[l];
                sum += H[((size_t)p * BB + b) * 288 + d];
            }
            v = sum / (float)cnt;
        }
        out[((size_t)b * NV + n) * 288 + d] = v;
    }
}

// ============================================================
// Launch
// ============================================================
extern "C" void kernel_launch(void* const* d_in, const int* in_sizes, int n_in,
                              void* d_out, int out_size, void* d_ws, size_t ws_size,
                              hipStream_t stream) {
    const float* X   = (const float*)d_in[0];
    const float* Xd  = (const float*)d_in[1];
    const float* Xw  = (const float*)d_in[2];
    const float* c1w = (const float*)d_in[4];
    const float* c1b = (const float*)d_in[5];
    const float* c2w = (const float*)d_in[6];
    const float* c2b = (const float*)d_in[7];
    const float* W1  = (const float*)d_in[8];
    const float* W2  = (const float*)d_in[9];
    const float* W3  = (const float*)d_in[10];
    const float* bs  = (const float*)d_in[11];
    const float* Vs  = (const float*)d_in[12];
    const float* fcw = (const float*)d_in[13];
    const float* fcb = (const float*)d_in[14];
    float* out = (float*)d_out;

    TreeBlob* pinned = get_pinned_tree();

    char* w = (char*)d_ws;
    auto alloc = [&](size_t bytes) { char* p = w; w += (bytes + 255) & ~(size_t)255; return p; };
    float*  x      = (float*)alloc((size_t)BB * NV * 288 * 4);
    float*  lhs    = (float*)alloc((size_t)BB * NV * 16 * 4);
    float*  rhs    = (float*)alloc((size_t)BB * NV * 16 * 4);
    float*  colsum = (float*)alloc((size_t)BB * NV * 4);
    float*  aedge  = (float*)alloc((size_t)NEDGES * BB * 4);
    float*  H      = (float*)alloc((size_t)NPATHS * BB * 288 * 4);
    float*  sAr    = (float*)alloc((size_t)NP2 * 4);
    float*  c0r    = (float*)alloc((size_t)NP2 * 4);
    int*    dtree  = (int*)alloc(sizeof(TreeBlob));
    int8_t* Vq     = (int8_t*)alloc((size_t)NP2 * LDKQ);
    int8_t* Sq     = (int8_t*)alloc((size_t)BB * NP2 * LDKQ);

    int* d_path   = dtree;
    int* d_lstart = dtree + NPATHS;
    int* d_lpath  = d_lstart + (NV + 1);

    hipFuncSetAttribute((const void*)k_gemm64, hipFuncAttributeMaxDynamicSharedMemorySize, 131072);

    hipMemcpyAsync(dtree, pinned, sizeof(TreeBlob), hipMemcpyHostToDevice, stream);

    k_timeblock<<<(BB * NV * 18 + 255) / 256, 256, 0, stream>>>(X, Xd, Xw, c1w, c1b, c2w, c2b, x);
    k_lhsrhs<<<(BB * NV + 255) / 256, 256, 0, stream>>>(x, W1, W2, W3, lhs, rhs);
    k_prep<<<NP2 + NSIGM * NSIGK, 256, 0, stream>>>(Vs, Vq, sAr, c0r, lhs, rhs, bs, Sq, colsum);
    k_gemm64<<<19 * 19 * BB, 512, 131072, stream>>>(Vq, Sq, sAr, c0r, colsum);
    k_edge<<<NEDGES, 256, 0, stream>>>(Vq, Sq, sAr, c0r, colsum, d_path, aedge);
    k_level<<<(1000 * BB * TPX + 255) / 256, 256, 0, stream>>>(x, d_path, fcw, fcb, aedge, H, 1000, 0, 500, 0, 1);
    k_level<<<(2000 * BB * TPX + 255) / 256, 256, 0, stream>>>(x, d_path, fcw, fcb, aedge, H, 2000, 500, 1500, 1000, 0);
    k_level<<<(4000 * BB * TPX + 255) / 256, 256, 0, stream>>>(x, d_path, fcw, fcb, aedge, H, 4000, 1500, 3500, 3000, 0);
    k_pool<<<NV, 256, 0, stream>>>(x, H, d_lstart, d_lpath, out);
}